// Round 9
// baseline (233.471 us; speedup 1.0000x reference)
//
#include <hip/hip_runtime.h>
#include <hip/hip_bf16.h>
#include <math.h>

#define DIM    1024
#define BATCH  2
#define SEQ    2048
#define NHEAD  16
#define HDIM   64
#define MROWS  (BATCH*SEQ)   // 4096
#define NSPLIT 8             // ktv S-splits

typedef unsigned short u16;
typedef __attribute__((ext_vector_type(8))) short  s16x8;   // 8 bf16 = 4 VGPRs
typedef __attribute__((ext_vector_type(4))) float  f32x4;

__device__ __forceinline__ float bf2f(u16 h) {
    unsigned u = ((unsigned)h) << 16; float f; __builtin_memcpy(&f, &u, 4); return f;
}
__device__ __forceinline__ u16 f2bf(float f) {
    unsigned u; __builtin_memcpy(&u, &f, 4);
    u += 0x7FFFu + ((u >> 16) & 1u);           // round-to-nearest-even
    return (u16)(u >> 16);
}
__device__ __forceinline__ unsigned pack_bf2(float a, float b) {
    __hip_bfloat162 h2 = __float22bfloat162_rn(float2{a, b});  // v_cvt_pk_bf16_f32
    unsigned r; __builtin_memcpy(&r, &h2, 4); return r;
}
__device__ __forceinline__ uint4 cvt8(float4 lo, float4 hi) {
    uint4 r;
    r.x = pack_bf2(lo.x, lo.y); r.y = pack_bf2(lo.z, lo.w);
    r.z = pack_bf2(hi.x, hi.y); r.w = pack_bf2(hi.z, hi.w);
    return r;
}

// ---------------------------------------------------------------------------
// fp32->bf16 pack for x + Wq/Wk/Wv (W1/W2 converted on the fly in MLP GEMMs).
// ---------------------------------------------------------------------------
__global__ __launch_bounds__(256)
void pack_all(const float* __restrict__ x,
              const float* __restrict__ Wq, const float* __restrict__ Wk,
              const float* __restrict__ Wv,
              u16* __restrict__ xb, u16* __restrict__ Wqb, u16* __restrict__ Wkb,
              u16* __restrict__ Wvb)
{
    const int bid = blockIdx.x;
    const float* src; u16* dst; int i;
    if (bid < 4096) { src = x; dst = xb; i = bid * 256 + threadIdx.x; }
    else {
        const int w = (bid - 4096) >> 10;
        const int lb = (bid - 4096) & 1023;
        src = (w == 0) ? Wq : (w == 1) ? Wk : Wv;
        dst = (w == 0) ? Wqb : (w == 1) ? Wkb : Wvb;
        i = lb * 256 + threadIdx.x;
    }
    float4 v = ((const float4*)src)[i];
    ushort4 o = { f2bf(v.x), f2bf(v.y), f2bf(v.z), f2bf(v.w) };
    ((ushort4*)dst)[i] = o;
}

// ---------------------------------------------------------------------------
// Register-staged pipelined GEMM core, tile 128x128, BK=32, 256 thr = 4 waves
// (2x2), wave tile 64x64 (4x4 MFMAs). Double-buffered LDS (32 KB), ONE
// barrier/iter: barrier -> issue loads(k+1) -> compute(cur) -> ds_write(next).
// A,B both bf16. (round-8 proven)
// ---------------------------------------------------------------------------
__device__ __forceinline__ void gemm_core_pf128(const u16* __restrict__ Ab,
                                                const u16* __restrict__ Bb,
                                                u16* As, u16* Bs,  // each 2*4096 u16
                                                int tid, f32x4 acc[4][4])
{
    const int w = tid >> 6, l = tid & 63;
    const int wm = (w >> 1) * 64, wn = (w & 1) * 64;
    const int lr = l & 15, kq = l >> 4;
    const int row = tid >> 2, cg8 = (tid & 3) * 8;

    const u16* a0 = Ab + (size_t)row * DIM + cg8;
    const u16* a1 = Ab + (size_t)(64 + row) * DIM + cg8;
    const u16* b0 = Bb + (size_t)row * DIM + cg8;
    const u16* b1 = Bb + (size_t)(64 + row) * DIM + cg8;

    uint4 pa0 = *(const uint4*)a0, pa1 = *(const uint4*)a1;
    uint4 pb0 = *(const uint4*)b0, pb1 = *(const uint4*)b1;
    *(uint4*)(As + tid * 8) = pa0;  *(uint4*)(As + 2048 + tid * 8) = pa1;
    *(uint4*)(Bs + tid * 8) = pb0;  *(uint4*)(Bs + 2048 + tid * 8) = pb1;

    const int NIT = DIM / 32;
    for (int it = 0; it < NIT; ++it) {
        u16* Ac = As + (it & 1) * 4096;
        u16* Bc = Bs + (it & 1) * 4096;
        __syncthreads();
        if (it + 1 < NIT) {
            const int k = (it + 1) * 32;
            pa0 = *(const uint4*)(a0 + k); pa1 = *(const uint4*)(a1 + k);
            pb0 = *(const uint4*)(b0 + k); pb1 = *(const uint4*)(b1 + k);
        }
        s16x8 af[4], bfr[4];
        #pragma unroll
        for (int i = 0; i < 4; ++i)
            af[i]  = *(const s16x8*)(Ac + (wm + i * 16 + lr) * 32 + kq * 8);
        #pragma unroll
        for (int j = 0; j < 4; ++j)
            bfr[j] = *(const s16x8*)(Bc + (wn + j * 16 + lr) * 32 + kq * 8);
        #pragma unroll
        for (int i = 0; i < 4; ++i)
            #pragma unroll
            for (int j = 0; j < 4; ++j)
                acc[i][j] = __builtin_amdgcn_mfma_f32_16x16x32_bf16(af[i], bfr[j], acc[i][j], 0, 0, 0);
        if (it + 1 < NIT) {
            u16* An = As + ((it + 1) & 1) * 4096;
            u16* Bn = Bs + ((it + 1) & 1) * 4096;
            *(uint4*)(An + tid * 8) = pa0;  *(uint4*)(An + 2048 + tid * 8) = pa1;
            *(uint4*)(Bn + tid * 8) = pb0;  *(uint4*)(Bn + 2048 + tid * 8) = pb1;
        }
    }
}

// ---------------------------------------------------------------------------
// Same pipeline/tile, A = bf16, B = fp32 source converted on the fly (RNE,
// v_cvt_pk_bf16_f32) during LDS staging. For the MLP GEMMs (B = W1/W2).
// ---------------------------------------------------------------------------
__device__ __forceinline__ void gemm_core_pf128_a16b32(const u16* __restrict__ Ab,
                                                       const float* __restrict__ Bf,
                                                       u16* As, u16* Bs,
                                                       int tid, f32x4 acc[4][4])
{
    const int w = tid >> 6, l = tid & 63;
    const int wm = (w >> 1) * 64, wn = (w & 1) * 64;
    const int lr = l & 15, kq = l >> 4;
    const int row = tid >> 2, cg8 = (tid & 3) * 8;

    const u16*   a0 = Ab + (size_t)row * DIM + cg8;
    const u16*   a1 = Ab + (size_t)(64 + row) * DIM + cg8;
    const float* b0 = Bf + (size_t)row * DIM + cg8;
    const float* b1 = Bf + (size_t)(64 + row) * DIM + cg8;

    uint4 pa0 = *(const uint4*)a0, pa1 = *(const uint4*)a1;
    float4 q00 = *(const float4*)b0, q01 = *(const float4*)(b0 + 4);
    float4 q10 = *(const float4*)b1, q11 = *(const float4*)(b1 + 4);
    *(uint4*)(As + tid * 8) = pa0;  *(uint4*)(As + 2048 + tid * 8) = pa1;
    *(uint4*)(Bs + tid * 8) = cvt8(q00, q01);
    *(uint4*)(Bs + 2048 + tid * 8) = cvt8(q10, q11);

    const int NIT = DIM / 32;
    for (int it = 0; it < NIT; ++it) {
        u16* Ac = As + (it & 1) * 4096;
        u16* Bc = Bs + (it & 1) * 4096;
        __syncthreads();
        if (it + 1 < NIT) {
            const int k = (it + 1) * 32;
            pa0 = *(const uint4*)(a0 + k); pa1 = *(const uint4*)(a1 + k);
            q00 = *(const float4*)(b0 + k); q01 = *(const float4*)(b0 + k + 4);
            q10 = *(const float4*)(b1 + k); q11 = *(const float4*)(b1 + k + 4);
        }
        s16x8 af[4], bfr[4];
        #pragma unroll
        for (int i = 0; i < 4; ++i)
            af[i]  = *(const s16x8*)(Ac + (wm + i * 16 + lr) * 32 + kq * 8);
        #pragma unroll
        for (int j = 0; j < 4; ++j)
            bfr[j] = *(const s16x8*)(Bc + (wn + j * 16 + lr) * 32 + kq * 8);
        #pragma unroll
        for (int i = 0; i < 4; ++i)
            #pragma unroll
            for (int j = 0; j < 4; ++j)
                acc[i][j] = __builtin_amdgcn_mfma_f32_16x16x32_bf16(af[i], bfr[j], acc[i][j], 0, 0, 0);
        if (it + 1 < NIT) {
            u16* An = As + ((it + 1) & 1) * 4096;
            u16* Bn = Bs + ((it + 1) & 1) * 4096;
            *(uint4*)(An + tid * 8) = pa0;  *(uint4*)(An + 2048 + tid * 8) = pa1;
            *(uint4*)(Bn + tid * 8) = cvt8(q00, q01);
            *(uint4*)(Bn + 2048 + tid * 8) = cvt8(q10, q11);
        }
    }
}

// ---------------------------------------------------------------------------
// Fused QKV projection: grid (24, 32), x = sel*8 + n-tile (24%8==0 so
// XCD = x%8 -> each XCD holds 3 weight n-tiles = 0.75 MB in its L2).
// ---------------------------------------------------------------------------
__global__ __launch_bounds__(256)
void qkv_gemm(const u16* __restrict__ xb,
              const u16* __restrict__ Wq, const u16* __restrict__ Wk, const u16* __restrict__ Wv,
              const float* __restrict__ bq, const float* __restrict__ bk, const float* __restrict__ bv,
              u16* __restrict__ qo, u16* __restrict__ ko, u16* __restrict__ vo)
{
    __shared__ u16 As[2 * 4096];
    __shared__ u16 Bs[2 * 4096];
    const int tid = threadIdx.x;
    const int sel = blockIdx.x >> 3;
    const int n0  = (blockIdx.x & 7) * 128;
    const int m0  = blockIdx.y * 128;
    const u16*   B    = (sel == 0) ? Wq : (sel == 1) ? Wk : Wv;
    const float* bias = (sel == 0) ? bq : (sel == 1) ? bk : bv;
    u16*         C    = (sel == 0) ? qo : (sel == 1) ? ko : vo;
    const float scale = (sel == 0) ? 0.125f : 1.0f;

    f32x4 acc[4][4];
    #pragma unroll
    for (int i = 0; i < 4; ++i)
        #pragma unroll
        for (int j = 0; j < 4; ++j) acc[i][j] = (f32x4){0.f, 0.f, 0.f, 0.f};

    gemm_core_pf128(xb + (size_t)m0 * DIM, B + (size_t)n0 * DIM, As, Bs, tid, acc);

    const int w = tid >> 6, l = tid & 63;
    const int wm = (w >> 1) * 64, wn = (w & 1) * 64;
    const int er = l >> 4, ec = l & 15;
    #pragma unroll
    for (int j = 0; j < 4; ++j) {
        const int n = n0 + wn + j * 16 + ec;
        const float bb = bias[n];
        #pragma unroll
        for (int i = 0; i < 4; ++i)
            #pragma unroll
            for (int r = 0; r < 4; ++r) {
                const int m = m0 + wm + i * 16 + er * 4 + r;
                C[(size_t)m * DIM + n] = f2bf((acc[i][j][r] + bb) * scale);
            }
    }
}

// ---------------------------------------------------------------------------
// MLP GEMMs: 128x128 tile, grid (8 n-tiles, 32 m-tiles) = 256 blocks (1/CU);
// XCD = blockIdx.x%8 -> 0.5 MB fp32 weight tile per XCD. B = fp32 weights,
// converted on the fly. mode 1: gelu -> bf16.  mode 2: +bias +x +attn -> fp32.
// ---------------------------------------------------------------------------
__global__ __launch_bounds__(256)
void gemm_mlp(const u16* __restrict__ A, const float* __restrict__ Bf,
              const float* __restrict__ bias,
              u16* __restrict__ Cb, float* __restrict__ Cf,
              const float* __restrict__ rx, const u16* __restrict__ rattn,
              int mode)
{
    __shared__ u16 As[2 * 4096];
    __shared__ u16 Bs[2 * 4096];
    const int tid = threadIdx.x;
    const int n0 = blockIdx.x * 128, m0 = blockIdx.y * 128;

    f32x4 acc[4][4];
    #pragma unroll
    for (int i = 0; i < 4; ++i)
        #pragma unroll
        for (int j = 0; j < 4; ++j) acc[i][j] = (f32x4){0.f, 0.f, 0.f, 0.f};

    gemm_core_pf128_a16b32(A + (size_t)m0 * DIM, Bf + (size_t)n0 * DIM, As, Bs, tid, acc);

    const int w = tid >> 6, l = tid & 63;
    const int wm = (w >> 1) * 64, wn = (w & 1) * 64;
    const int er = l >> 4, ec = l & 15;
    #pragma unroll
    for (int j = 0; j < 4; ++j) {
        const int n = n0 + wn + j * 16 + ec;
        const float bb = bias[n];
        #pragma unroll
        for (int i = 0; i < 4; ++i)
            #pragma unroll
            for (int r = 0; r < 4; ++r) {
                const int m = m0 + wm + i * 16 + er * 4 + r;
                const size_t idx = (size_t)m * DIM + n;
                float v = acc[i][j][r] + bb;
                if (mode == 1) {
                    v = 0.5f * v * (1.0f + erff(v * 0.70710678118654752f));
                    Cb[idx] = f2bf(v);
                } else {
                    Cf[idx] = v + rx[idx] + bf2f(rattn[idx]);
                }
            }
    }
}

// ---------------------------------------------------------------------------
// ktv via MFMA, no atomics. grid 256 = 32 (b,h) x 8 s-splits, 256 threads.
// ---------------------------------------------------------------------------
__global__ __launch_bounds__(256)
void ktv_mfma(const u16* __restrict__ Kb, const u16* __restrict__ Vb,
              float* __restrict__ part)
{
    __shared__ u16 Kt[64 * 264];
    __shared__ u16 Vt[64 * 264];
    const int tid = threadIdx.x;
    const int bh = blockIdx.x & 31;
    const int sp = blockIdx.x >> 5;
    const int b = bh >> 4, h = bh & 15;
    const size_t base = (size_t)b * SEQ * DIM + (size_t)h * HDIM + (size_t)sp * 256 * DIM;

    const int dg = (tid & 15) * 4;
    #pragma unroll
    for (int pass = 0; pass < 16; ++pass) {
        const int s = (tid >> 4) + 16 * pass;
        ushort4 kv = *(const ushort4*)(Kb + base + (size_t)s * DIM + dg);
        ushort4 vv = *(const ushort4*)(Vb + base + (size_t)s * DIM + dg);
        Kt[(dg + 0) * 264 + s] = kv.x; Kt[(dg + 1) * 264 + s] = kv.y;
        Kt[(dg + 2) * 264 + s] = kv.z; Kt[(dg + 3) * 264 + s] = kv.w;
        Vt[(dg + 0) * 264 + s] = vv.x; Vt[(dg + 1) * 264 + s] = vv.y;
        Vt[(dg + 2) * 264 + s] = vv.z; Vt[(dg + 3) * 264 + s] = vv.w;
    }
    __syncthreads();

    const int w = tid >> 6, l = tid & 63;
    const int lr = l & 15, kq = l >> 4;
    f32x4 acc[4];
    #pragma unroll
    for (int j = 0; j < 4; ++j) acc[j] = (f32x4){0.f, 0.f, 0.f, 0.f};

    for (int k0 = 0; k0 < 256; k0 += 32) {
        s16x8 af = *(const s16x8*)(Kt + (w * 16 + lr) * 264 + k0 + kq * 8);
        #pragma unroll
        for (int j = 0; j < 4; ++j) {
            s16x8 bf = *(const s16x8*)(Vt + (j * 16 + lr) * 264 + k0 + kq * 8);
            acc[j] = __builtin_amdgcn_mfma_f32_16x16x32_bf16(af, bf, acc[j], 0, 0, 0);
        }
    }

    float* dst = part + ((size_t)sp * 32 + bh) * (HDIM * HDIM);
    const int er = l >> 4, ec = l & 15;
    #pragma unroll
    for (int j = 0; j < 4; ++j)
        #pragma unroll
        for (int r = 0; r < 4; ++r)
            dst[(w * 16 + er * 4 + r) * HDIM + j * 16 + ec] = acc[j][r];
}

// ---------------------------------------------------------------------------
// attn = Q @ KtV (block-diag per head), fused partial-reduction.
// ---------------------------------------------------------------------------
__global__ __launch_bounds__(256)
void qktv_kernel(const u16* __restrict__ Qb, const float* __restrict__ part,
                 u16* __restrict__ attnb)
{
    __shared__ float KV[HDIM * HDIM];
    __shared__ u16 Qs[128 * 68];
    const int tid = threadIdx.x;
    const int h  = blockIdx.x;
    const int mt = blockIdx.y;
    const int row0 = mt * 128;
    const int b = row0 >> 11;
    const int bh = b * NHEAD + h;

    for (int i = tid; i < HDIM * HDIM; i += 256) {
        float s = 0.f;
        #pragma unroll
        for (int sp = 0; sp < NSPLIT; ++sp)
            s += part[((size_t)sp * 32 + bh) * (HDIM * HDIM) + i];
        KV[i] = s;
    }
    const int dg = (tid & 15) * 4;
    #pragma unroll
    for (int pass = 0; pass < 8; ++pass) {
        const int r = (tid >> 4) + 16 * pass;
        ushort4 q = *(const ushort4*)(Qb + (size_t)(row0 + r) * DIM + h * HDIM + dg);
        *(ushort4*)(Qs + r * 68 + dg) = q;
    }
    __syncthreads();

    const int tr = tid >> 3, tc = tid & 7;
    const int r0 = tr * 4, c0 = tc * 8;
    float acc[4][8] = {};
    for (int d = 0; d < HDIM; ++d) {
        float4 ka  = *(const float4*)&KV[d * HDIM + c0];
        float4 kb2 = *(const float4*)&KV[d * HDIM + c0 + 4];
        const float* k8a = (const float*)&ka;
        const float* k8b = (const float*)&kb2;
        float qv[4];
        #pragma unroll
        for (int i = 0; i < 4; ++i) qv[i] = bf2f(Qs[(r0 + i) * 68 + d]);
        #pragma unroll
        for (int i = 0; i < 4; ++i)
            #pragma unroll
            for (int j = 0; j < 4; ++j) {
                acc[i][j]     += qv[i] * k8a[j];
                acc[i][j + 4] += qv[i] * k8b[j];
            }
    }
    #pragma unroll
    for (int i = 0; i < 4; ++i) {
        u16* dst = attnb + (size_t)(row0 + r0 + i) * DIM + h * HDIM + c0;
        ushort4 o0 = { f2bf(acc[i][0]), f2bf(acc[i][1]), f2bf(acc[i][2]), f2bf(acc[i][3]) };
        ushort4 o1 = { f2bf(acc[i][4]), f2bf(acc[i][5]), f2bf(acc[i][6]), f2bf(acc[i][7]) };
        *(ushort4*)(dst)     = o0;
        *(ushort4*)(dst + 4) = o1;
    }
}

// ---------------------------------------------------------------------------
extern "C" void kernel_launch(void* const* d_in, const int* in_sizes, int n_in,
                              void* d_out, int out_size, void* d_ws, size_t ws_size,
                              hipStream_t stream)
{
    const float* x  = (const float*)d_in[0];
    const float* Wq = (const float*)d_in[1];
    const float* bq = (const float*)d_in[2];
    const float* Wk = (const float*)d_in[3];
    const float* bk = (const float*)d_in[4];
    const float* Wv = (const float*)d_in[5];
    const float* bv = (const float*)d_in[6];
    const float* W1 = (const float*)d_in[7];
    const float* b1 = (const float*)d_in[8];
    const float* W2 = (const float*)d_in[9];
    const float* b2 = (const float*)d_in[10];
    float* out = (float*)d_out;

    char* ws = (char*)d_ws;
    const size_t MB = 1u << 20;
    u16* xb   = (u16*)(ws);              //  8 MB
    u16* Wqb  = (u16*)(ws +  8 * MB);    //  2 MB each
    u16* Wkb  = (u16*)(ws + 10 * MB);
    u16* Wvb  = (u16*)(ws + 12 * MB);
    u16* qb   = (u16*)(ws + 18 * MB);    //  8 MB
    u16* kb   = (u16*)(ws + 26 * MB);    //  8 MB
    u16* vb   = (u16*)(ws + 34 * MB);    //  8 MB
    float* part = (float*)(ws + 42 * MB);//  4 MB
    u16* attnb = kb;
    u16* h1b   = vb;

    pack_all<<<4096 + 3 * 1024, 256, 0, stream>>>(x, Wq, Wk, Wv, xb, Wqb, Wkb, Wvb);

    // x = sel*8 + n-tile (XCD-local weight tiles), y = m-tile
    qkv_gemm<<<dim3(24, 32), 256, 0, stream>>>(xb, Wqb, Wkb, Wvb, bq, bk, bv, qb, kb, vb);

    ktv_mfma<<<NSPLIT * 32, 256, 0, stream>>>(kb, vb, part);
    qktv_kernel<<<dim3(NHEAD, MROWS / 128), 256, 0, stream>>>(qb, part, attnb);

    // x = n-tile (8), y = m-tile (32): 256 blocks, 1/CU, XCD-local weights
    gemm_mlp<<<dim3(8, 32), 256, 0, stream>>>(attnb, W1, b1, h1b, nullptr, nullptr, nullptr, 1);
    gemm_mlp<<<dim3(8, 32), 256, 0, stream>>>(h1b, W2, b2, nullptr, out, x, attnb, 2);
}

// Round 10
// 204.408 us; speedup vs baseline: 1.1422x; 1.1422x over previous
//
#include <hip/hip_runtime.h>
#include <hip/hip_bf16.h>
#include <math.h>

#define DIM    1024
#define BATCH  2
#define SEQ    2048
#define NHEAD  16
#define HDIM   64
#define MROWS  (BATCH*SEQ)   // 4096
#define NSPLIT 8             // ktv S-splits

typedef unsigned short u16;
typedef __attribute__((ext_vector_type(8))) short  s16x8;   // 8 bf16 = 4 VGPRs
typedef __attribute__((ext_vector_type(4))) float  f32x4;

__device__ __forceinline__ float bf2f(u16 h) {
    unsigned u = ((unsigned)h) << 16; float f; __builtin_memcpy(&f, &u, 4); return f;
}
__device__ __forceinline__ u16 f2bf(float f) {
    unsigned u; __builtin_memcpy(&u, &f, 4);
    u += 0x7FFFu + ((u >> 16) & 1u);           // round-to-nearest-even
    return (u16)(u >> 16);
}
__device__ __forceinline__ unsigned pack_bf2(float a, float b) {
    __hip_bfloat162 h2 = __float22bfloat162_rn(float2{a, b});  // v_cvt_pk_bf16_f32
    unsigned r; __builtin_memcpy(&r, &h2, 4); return r;
}
__device__ __forceinline__ uint4 cvt8(float4 lo, float4 hi) {
    uint4 r;
    r.x = pack_bf2(lo.x, lo.y); r.y = pack_bf2(lo.z, lo.w);
    r.z = pack_bf2(hi.x, hi.y); r.w = pack_bf2(hi.z, hi.w);
    return r;
}

// ---------------------------------------------------------------------------
// fp32->bf16 pack for the 5 weight matrices (x converted on the fly in qkv).
// ---------------------------------------------------------------------------
__global__ __launch_bounds__(256)
void pack5(const float* __restrict__ Wq, const float* __restrict__ Wk,
           const float* __restrict__ Wv, const float* __restrict__ W1,
           const float* __restrict__ W2,
           u16* __restrict__ Wqb, u16* __restrict__ Wkb, u16* __restrict__ Wvb,
           u16* __restrict__ W1b, u16* __restrict__ W2b)
{
    const int w  = blockIdx.x >> 10;
    const int lb = blockIdx.x & 1023;
    const float* src = (w == 0) ? Wq : (w == 1) ? Wk : (w == 2) ? Wv : (w == 3) ? W1 : W2;
    u16*         dst = (w == 0) ? Wqb : (w == 1) ? Wkb : (w == 2) ? Wvb : (w == 3) ? W1b : W2b;
    const int i = lb * 256 + threadIdx.x;
    float4 v = ((const float4*)src)[i];
    ushort4 o = { f2bf(v.x), f2bf(v.y), f2bf(v.z), f2bf(v.w) };
    ((ushort4*)dst)[i] = o;
}

// ---------------------------------------------------------------------------
// Register-staged pipelined GEMM core, tile 128x128, BK=32, 256 thr = 4 waves
// (2x2), wave tile 64x64 (4x4 MFMAs). Double-buffered LDS (32 KB), ONE
// barrier/iter: barrier -> issue loads(k+1) -> compute(cur) -> ds_write(next).
// A = fp32 source (RNE-converted while staging), B = bf16.  (qkv variant)
// ---------------------------------------------------------------------------
__device__ __forceinline__ void gemm_core_pf128_a32(const float* __restrict__ Af,
                                                    const u16* __restrict__ Bb,
                                                    u16* As, u16* Bs,  // each 2*4096 u16
                                                    int tid, f32x4 acc[4][4])
{
    const int w = tid >> 6, l = tid & 63;
    const int wm = (w >> 1) * 64, wn = (w & 1) * 64;
    const int lr = l & 15, kq = l >> 4;
    const int row = tid >> 2, cg8 = (tid & 3) * 8;

    const float* a0 = Af + (size_t)row * DIM + cg8;
    const float* a1 = Af + (size_t)(64 + row) * DIM + cg8;
    const u16*   b0 = Bb + (size_t)row * DIM + cg8;
    const u16*   b1 = Bb + (size_t)(64 + row) * DIM + cg8;

    float4 qa00 = *(const float4*)a0, qa01 = *(const float4*)(a0 + 4);
    float4 qa10 = *(const float4*)a1, qa11 = *(const float4*)(a1 + 4);
    uint4 pb0 = *(const uint4*)b0, pb1 = *(const uint4*)b1;
    *(uint4*)(As + tid * 8) = cvt8(qa00, qa01);
    *(uint4*)(As + 2048 + tid * 8) = cvt8(qa10, qa11);
    *(uint4*)(Bs + tid * 8) = pb0;  *(uint4*)(Bs + 2048 + tid * 8) = pb1;

    const int NIT = DIM / 32;
    for (int it = 0; it < NIT; ++it) {
        u16* Ac = As + (it & 1) * 4096;
        u16* Bc = Bs + (it & 1) * 4096;
        __syncthreads();
        if (it + 1 < NIT) {
            const int k = (it + 1) * 32;
            qa00 = *(const float4*)(a0 + k); qa01 = *(const float4*)(a0 + k + 4);
            qa10 = *(const float4*)(a1 + k); qa11 = *(const float4*)(a1 + k + 4);
            pb0 = *(const uint4*)(b0 + k);   pb1 = *(const uint4*)(b1 + k);
        }
        s16x8 af[4], bfr[4];
        #pragma unroll
        for (int i = 0; i < 4; ++i)
            af[i]  = *(const s16x8*)(Ac + (wm + i * 16 + lr) * 32 + kq * 8);
        #pragma unroll
        for (int j = 0; j < 4; ++j)
            bfr[j] = *(const s16x8*)(Bc + (wn + j * 16 + lr) * 32 + kq * 8);
        #pragma unroll
        for (int i = 0; i < 4; ++i)
            #pragma unroll
            for (int j = 0; j < 4; ++j)
                acc[i][j] = __builtin_amdgcn_mfma_f32_16x16x32_bf16(af[i], bfr[j], acc[i][j], 0, 0, 0);
        if (it + 1 < NIT) {
            u16* An = As + ((it + 1) & 1) * 4096;
            u16* Bn = Bs + ((it + 1) & 1) * 4096;
            *(uint4*)(An + tid * 8) = cvt8(qa00, qa01);
            *(uint4*)(An + 2048 + tid * 8) = cvt8(qa10, qa11);
            *(uint4*)(Bn + tid * 8) = pb0;  *(uint4*)(Bn + 2048 + tid * 8) = pb1;
        }
    }
}

// ---------------------------------------------------------------------------
// Register-staged pipeline, tile 64x128 (MLP shape), 4 waves (2m x 2n),
// wave 32x64. LDS 2*(4+8) = 24 KB. A,B bf16.  (round-8 proven)
// ---------------------------------------------------------------------------
__device__ __forceinline__ void gemm_core_pf64(const u16* __restrict__ Ab,
                                               const u16* __restrict__ Bb,
                                               u16* As /*2*2048*/, u16* Bs /*2*4096*/,
                                               int tid, f32x4 acc[2][4])
{
    const int w  = tid >> 6, l = tid & 63;
    const int wm = (w >> 1) * 32, wn = (w & 1) * 64;
    const int lr = l & 15, kq = l >> 4;
    const int row = tid >> 2, cg8 = (tid & 3) * 8;

    const u16* a0 = Ab + (size_t)row * DIM + cg8;
    const u16* b0 = Bb + (size_t)row * DIM + cg8;
    const u16* b1 = Bb + (size_t)(64 + row) * DIM + cg8;

    uint4 pa  = *(const uint4*)a0;
    uint4 pb0 = *(const uint4*)b0, pb1 = *(const uint4*)b1;
    *(uint4*)(As + tid * 8) = pa;
    *(uint4*)(Bs + tid * 8) = pb0; *(uint4*)(Bs + 2048 + tid * 8) = pb1;

    const int NIT = DIM / 32;
    for (int it = 0; it < NIT; ++it) {
        u16* Ac = As + (it & 1) * 2048;
        u16* Bc = Bs + (it & 1) * 4096;
        __syncthreads();
        if (it + 1 < NIT) {
            const int k = (it + 1) * 32;
            pa  = *(const uint4*)(a0 + k);
            pb0 = *(const uint4*)(b0 + k); pb1 = *(const uint4*)(b1 + k);
        }
        s16x8 af[2], bfr[4];
        #pragma unroll
        for (int i = 0; i < 2; ++i)
            af[i]  = *(const s16x8*)(Ac + (wm + i * 16 + lr) * 32 + kq * 8);
        #pragma unroll
        for (int j = 0; j < 4; ++j)
            bfr[j] = *(const s16x8*)(Bc + (wn + j * 16 + lr) * 32 + kq * 8);
        #pragma unroll
        for (int i = 0; i < 2; ++i)
            #pragma unroll
            for (int j = 0; j < 4; ++j)
                acc[i][j] = __builtin_amdgcn_mfma_f32_16x16x32_bf16(af[i], bfr[j], acc[i][j], 0, 0, 0);
        if (it + 1 < NIT) {
            u16* An = As + ((it + 1) & 1) * 2048;
            u16* Bn = Bs + ((it + 1) & 1) * 4096;
            *(uint4*)(An + tid * 8) = pa;
            *(uint4*)(Bn + tid * 8) = pb0; *(uint4*)(Bn + 2048 + tid * 8) = pb1;
        }
    }
}

// ---------------------------------------------------------------------------
// Fused QKV projection: 1D grid 768 with 2D XCD decode.
// XCD k = id%8 owns m-tiles ≡ k (mod 4) and one half of the 24 weight tiles:
//   per-XCD working set ≈ 4 MB x-slab + 3 MB weights; x duplicated only 2x,
//   weights 4x (vs 8x x-duplication of the 2D-grid variant).
// A = x fp32 (converted on the fly), B = packed bf16 weights.
// ---------------------------------------------------------------------------
__global__ __launch_bounds__(256)
void qkv_gemm(const float* __restrict__ xf,
              const u16* __restrict__ Wq, const u16* __restrict__ Wk, const u16* __restrict__ Wv,
              const float* __restrict__ bq, const float* __restrict__ bk, const float* __restrict__ bv,
              u16* __restrict__ qo, u16* __restrict__ ko, u16* __restrict__ vo)
{
    __shared__ u16 As[2 * 4096];
    __shared__ u16 Bs[2 * 4096];
    const int tid = threadIdx.x;
    const int id = blockIdx.x;
    const int k8 = id & 7, j = id >> 3;          // XCD, job
    const int m0 = ((k8 & 3) + 4 * (j & 7)) * 128;
    const int wsel = (k8 >> 2) * 12 + (j >> 3);  // 0..23 = sel*8 + ntile
    const int sel = wsel >> 3;
    const int n0  = (wsel & 7) * 128;
    const u16*   B    = (sel == 0) ? Wq : (sel == 1) ? Wk : Wv;
    const float* bias = (sel == 0) ? bq : (sel == 1) ? bk : bv;
    u16*         C    = (sel == 0) ? qo : (sel == 1) ? ko : vo;
    const float scale = (sel == 0) ? 0.125f : 1.0f;

    f32x4 acc[4][4];
    #pragma unroll
    for (int i = 0; i < 4; ++i)
        #pragma unroll
        for (int jj = 0; jj < 4; ++jj) acc[i][jj] = (f32x4){0.f, 0.f, 0.f, 0.f};

    gemm_core_pf128_a32(xf + (size_t)m0 * DIM, B + (size_t)n0 * DIM, As, Bs, tid, acc);

    const int w = tid >> 6, l = tid & 63;
    const int wm = (w >> 1) * 64, wn = (w & 1) * 64;
    const int er = l >> 4, ec = l & 15;
    #pragma unroll
    for (int jj = 0; jj < 4; ++jj) {
        const int n = n0 + wn + jj * 16 + ec;
        const float bb = bias[n];
        #pragma unroll
        for (int i = 0; i < 4; ++i)
            #pragma unroll
            for (int r = 0; r < 4; ++r) {
                const int m = m0 + wm + i * 16 + er * 4 + r;
                C[(size_t)m * DIM + n] = f2bf((acc[i][jj][r] + bb) * scale);
            }
    }
}

// ---------------------------------------------------------------------------
// MLP GEMMs: 256 threads, grid (64 m-tiles, 8 n-tiles) = 512 blocks (2/CU),
// tile 64x128. XCD = m%8 -> A-slab (1 MB) + full weights (2 MB) per XCD L2.
// mode 1: gelu -> bf16.   mode 2: +bias +x +attn -> fp32.
// ---------------------------------------------------------------------------
__global__ __launch_bounds__(256)
void gemm_bf16(const u16* __restrict__ A, const u16* __restrict__ B,
               const float* __restrict__ bias,
               u16* __restrict__ Cb, float* __restrict__ Cf,
               const float* __restrict__ rx, const u16* __restrict__ rattn,
               int mode)
{
    __shared__ u16 As[2 * 2048];
    __shared__ u16 Bs[2 * 4096];
    const int tid = threadIdx.x;
    const int m0 = blockIdx.x * 64, n0 = blockIdx.y * 128;

    f32x4 acc[2][4];
    #pragma unroll
    for (int i = 0; i < 2; ++i)
        #pragma unroll
        for (int j = 0; j < 4; ++j) acc[i][j] = (f32x4){0.f, 0.f, 0.f, 0.f};

    gemm_core_pf64(A + (size_t)m0 * DIM, B + (size_t)n0 * DIM, As, Bs, tid, acc);

    const int w = tid >> 6, l = tid & 63;
    const int wm = (w >> 1) * 32, wn = (w & 1) * 64;
    const int er = l >> 4, ec = l & 15;
    #pragma unroll
    for (int j = 0; j < 4; ++j) {
        const int n = n0 + wn + j * 16 + ec;
        const float bb = bias[n];
        #pragma unroll
        for (int i = 0; i < 2; ++i)
            #pragma unroll
            for (int r = 0; r < 4; ++r) {
                const int m = m0 + wm + i * 16 + er * 4 + r;
                const size_t idx = (size_t)m * DIM + n;
                float v = acc[i][j][r] + bb;
                if (mode == 1) {
                    v = 0.5f * v * (1.0f + erff(v * 0.70710678118654752f));
                    Cb[idx] = f2bf(v);
                } else {
                    Cf[idx] = v + rx[idx] + bf2f(rattn[idx]);
                }
            }
    }
}

// ---------------------------------------------------------------------------
// ktv via MFMA, no atomics. grid 256 = 32 (b,h) x 8 s-splits, 256 threads.
// ---------------------------------------------------------------------------
__global__ __launch_bounds__(256)
void ktv_mfma(const u16* __restrict__ Kb, const u16* __restrict__ Vb,
              float* __restrict__ part)
{
    __shared__ u16 Kt[64 * 264];
    __shared__ u16 Vt[64 * 264];
    const int tid = threadIdx.x;
    const int bh = blockIdx.x & 31;
    const int sp = blockIdx.x >> 5;
    const int b = bh >> 4, h = bh & 15;
    const size_t base = (size_t)b * SEQ * DIM + (size_t)h * HDIM + (size_t)sp * 256 * DIM;

    const int dg = (tid & 15) * 4;
    #pragma unroll
    for (int pass = 0; pass < 16; ++pass) {
        const int s = (tid >> 4) + 16 * pass;
        ushort4 kv = *(const ushort4*)(Kb + base + (size_t)s * DIM + dg);
        ushort4 vv = *(const ushort4*)(Vb + base + (size_t)s * DIM + dg);
        Kt[(dg + 0) * 264 + s] = kv.x; Kt[(dg + 1) * 264 + s] = kv.y;
        Kt[(dg + 2) * 264 + s] = kv.z; Kt[(dg + 3) * 264 + s] = kv.w;
        Vt[(dg + 0) * 264 + s] = vv.x; Vt[(dg + 1) * 264 + s] = vv.y;
        Vt[(dg + 2) * 264 + s] = vv.z; Vt[(dg + 3) * 264 + s] = vv.w;
    }
    __syncthreads();

    const int w = tid >> 6, l = tid & 63;
    const int lr = l & 15, kq = l >> 4;
    f32x4 acc[4];
    #pragma unroll
    for (int j = 0; j < 4; ++j) acc[j] = (f32x4){0.f, 0.f, 0.f, 0.f};

    for (int k0 = 0; k0 < 256; k0 += 32) {
        s16x8 af = *(const s16x8*)(Kt + (w * 16 + lr) * 264 + k0 + kq * 8);
        #pragma unroll
        for (int j = 0; j < 4; ++j) {
            s16x8 bf = *(const s16x8*)(Vt + (j * 16 + lr) * 264 + k0 + kq * 8);
            acc[j] = __builtin_amdgcn_mfma_f32_16x16x32_bf16(af, bf, acc[j], 0, 0, 0);
        }
    }

    float* dst = part + ((size_t)sp * 32 + bh) * (HDIM * HDIM);
    const int er = l >> 4, ec = l & 15;
    #pragma unroll
    for (int j = 0; j < 4; ++j)
        #pragma unroll
        for (int r = 0; r < 4; ++r)
            dst[(w * 16 + er * 4 + r) * HDIM + j * 16 + ec] = acc[j][r];
}

// ---------------------------------------------------------------------------
// attn = Q @ KtV (block-diag per head), fused partial-reduction.
// ---------------------------------------------------------------------------
__global__ __launch_bounds__(256)
void qktv_kernel(const u16* __restrict__ Qb, const float* __restrict__ part,
                 u16* __restrict__ attnb)
{
    __shared__ float KV[HDIM * HDIM];
    __shared__ u16 Qs[128 * 68];
    const int tid = threadIdx.x;
    const int h  = blockIdx.x;
    const int mt = blockIdx.y;
    const int row0 = mt * 128;
    const int b = row0 >> 11;
    const int bh = b * NHEAD + h;

    for (int i = tid; i < HDIM * HDIM; i += 256) {
        float s = 0.f;
        #pragma unroll
        for (int sp = 0; sp < NSPLIT; ++sp)
            s += part[((size_t)sp * 32 + bh) * (HDIM * HDIM) + i];
        KV[i] = s;
    }
    const int dg = (tid & 15) * 4;
    #pragma unroll
    for (int pass = 0; pass < 8; ++pass) {
        const int r = (tid >> 4) + 16 * pass;
        ushort4 q = *(const ushort4*)(Qb + (size_t)(row0 + r) * DIM + h * HDIM + dg);
        *(ushort4*)(Qs + r * 68 + dg) = q;
    }
    __syncthreads();

    const int tr = tid >> 3, tc = tid & 7;
    const int r0 = tr * 4, c0 = tc * 8;
    float acc[4][8] = {};
    for (int d = 0; d < HDIM; ++d) {
        float4 ka  = *(const float4*)&KV[d * HDIM + c0];
        float4 kb2 = *(const float4*)&KV[d * HDIM + c0 + 4];
        const float* k8a = (const float*)&ka;
        const float* k8b = (const float*)&kb2;
        float qv[4];
        #pragma unroll
        for (int i = 0; i < 4; ++i) qv[i] = bf2f(Qs[(r0 + i) * 68 + d]);
        #pragma unroll
        for (int i = 0; i < 4; ++i)
            #pragma unroll
            for (int j = 0; j < 4; ++j) {
                acc[i][j]     += qv[i] * k8a[j];
                acc[i][j + 4] += qv[i] * k8b[j];
            }
    }
    #pragma unroll
    for (int i = 0; i < 4; ++i) {
        u16* dst = attnb + (size_t)(row0 + r0 + i) * DIM + h * HDIM + c0;
        ushort4 o0 = { f2bf(acc[i][0]), f2bf(acc[i][1]), f2bf(acc[i][2]), f2bf(acc[i][3]) };
        ushort4 o1 = { f2bf(acc[i][4]), f2bf(acc[i][5]), f2bf(acc[i][6]), f2bf(acc[i][7]) };
        *(ushort4*)(dst)     = o0;
        *(ushort4*)(dst + 4) = o1;
    }
}

// ---------------------------------------------------------------------------
extern "C" void kernel_launch(void* const* d_in, const int* in_sizes, int n_in,
                              void* d_out, int out_size, void* d_ws, size_t ws_size,
                              hipStream_t stream)
{
    const float* x  = (const float*)d_in[0];
    const float* Wq = (const float*)d_in[1];
    const float* bq = (const float*)d_in[2];
    const float* Wk = (const float*)d_in[3];
    const float* bk = (const float*)d_in[4];
    const float* Wv = (const float*)d_in[5];
    const float* bv = (const float*)d_in[6];
    const float* W1 = (const float*)d_in[7];
    const float* b1 = (const float*)d_in[8];
    const float* W2 = (const float*)d_in[9];
    const float* b2 = (const float*)d_in[10];
    float* out = (float*)d_out;

    char* ws = (char*)d_ws;
    const size_t MB = 1u << 20;
    u16* Wqb  = (u16*)(ws);              //  2 MB each
    u16* Wkb  = (u16*)(ws +  2 * MB);
    u16* Wvb  = (u16*)(ws +  4 * MB);
    u16* W1b  = (u16*)(ws +  6 * MB);
    u16* W2b  = (u16*)(ws +  8 * MB);
    u16* qb   = (u16*)(ws + 10 * MB);    //  8 MB
    u16* kb   = (u16*)(ws + 18 * MB);    //  8 MB
    u16* vb   = (u16*)(ws + 26 * MB);    //  8 MB
    float* part = (float*)(ws + 34 * MB);//  4 MB
    u16* attnb = kb;
    u16* h1b   = vb;

    pack5<<<5 * 1024, 256, 0, stream>>>(Wq, Wk, Wv, W1, W2, Wqb, Wkb, Wvb, W1b, W2b);

    // 1D grid, 2D XCD decode; A = x fp32 converted on the fly
    qkv_gemm<<<768, 256, 0, stream>>>(x, Wqb, Wkb, Wvb, bq, bk, bv, qb, kb, vb);

    ktv_mfma<<<NSPLIT * 32, 256, 0, stream>>>(kb, vb, part);
    qktv_kernel<<<dim3(NHEAD, MROWS / 128), 256, 0, stream>>>(qb, part, attnb);

    gemm_bf16<<<dim3(64, 8), 256, 0, stream>>>(attnb, W1b, b1, h1b, nullptr, nullptr, nullptr, 1);
    gemm_bf16<<<dim3(64, 8), 256, 0, stream>>>(h1b, W2b, b2, nullptr, out, x, attnb, 2);
}